// Round 16
// baseline (331.651 us; speedup 1.0000x reference)
//
#include <hip/hip_runtime.h>
#include <hip/hip_bf16.h>
#include <hip/hip_fp16.h>

using u16 = unsigned short;
using u32 = unsigned int;
using u64 = unsigned long long;

typedef __attribute__((ext_vector_type(8))) short short8;
typedef __attribute__((ext_vector_type(8))) _Float16 half8;
typedef __attribute__((ext_vector_type(4))) _Float16 half4;
typedef __attribute__((ext_vector_type(4))) float f32x4;
typedef __attribute__((ext_vector_type(2))) u32 u32x2;

#define DEVI static __device__ __forceinline__

DEVI float bfu2f(u16 u) { return __builtin_bit_cast(float, (u32)u << 16); }
DEVI u16 f2bfu(float f) { return __builtin_bit_cast(u16, __float2bfloat16(f)); }
DEVI u16 f2hu(float f) { return __builtin_bit_cast(u16, (_Float16)f); }

DEVI f32x4 mfma_f16_(half8 a, half8 b, f32x4 c) {
  return __builtin_amdgcn_mfma_f32_16x16x32_f16(a, b, c, 0, 0, 0);
}
DEVI f32x4 mfma16_f16_(half4 a, half4 b, f32x4 c) {
  return __builtin_amdgcn_mfma_f32_16x16x16f16(a, b, c, 0, 0, 0);
}

// global -> LDS async stage, 16B per lane, linear dest (wave-uniform base)
#define GLD_LDS16(src, dst) \
  __builtin_amdgcn_global_load_lds((const __attribute__((address_space(1))) void*)(src), \
                                   (__attribute__((address_space(3))) void*)(dst), 16, 0, 0)

#define BAR() __builtin_amdgcn_s_barrier()
#define VMCNT(n) asm volatile("s_waitcnt vmcnt(" #n ")" ::: "memory")

// ---------------------------------------------------------------------------
// constants
// ---------------------------------------------------------------------------
static constexpr int Bsz = 2, S = 2048, D = 1024, H = 16, HD = 64;
static constexpr int MROWS = Bsz * S;                              // 4096
static constexpr size_t OUT_ELEMS = (size_t)Bsz * S * D;           // 4194304
static constexpr float C_EXP2 = 0.18033688f;  // 0.125 * log2(e)
// ws offsets (bytes)
static constexpr size_t OFF_WT  = 0;          // 4 x f16 [1024][1024] = 8MB
static constexpr size_t OFF_Q   = 0x800000;   // f16 [4096][1024] 8MB
static constexpr size_t OFF_K   = 0x1000000;
static constexpr size_t OFF_V   = 0x1800000;
static constexpr size_t OFF_VT  = 0x2000000;  // f16 [B*H][64][2048]
static constexpr size_t OFF_O   = 0x2800000;  // f16 [4096][1024]
static constexpr size_t OFF_MB  = 0x3000000;  // u64 [2048][32]
static constexpr size_t OFF_FLG = 0x3080000;  // int

// ---------------------------------------------------------------------------
// dtype detect
// ---------------------------------------------------------------------------
__global__ __launch_bounds__(256) void detect_dtype(
    const u16* __restrict__ q, int* __restrict__ flag)
{
  __shared__ u32 red[256];
  const int tid = threadIdx.x;
  u32 mx = 0;
  for (int i = tid; i < 32768; i += 256) {
    u32 e = (q[2 * i] >> 7) & 0xFF;
    mx = mx > e ? mx : e;
  }
  red[tid] = mx;
  __syncthreads();
  if (tid == 0) {
    u32 m = 0;
    for (int i = 0; i < 256; ++i) m = m > red[i] ? m : red[i];
    flag[0] = (m >= 0x90) ? 1 : 0;
  }
}

// ---------------------------------------------------------------------------
// W transpose + convert to f16: W[K][N] (f32|bf16) -> WT[z][N][K] f16
// ---------------------------------------------------------------------------
__global__ __launch_bounds__(256) void prep_w(
    const void* __restrict__ Wq, const void* __restrict__ Wk,
    const void* __restrict__ Wv, const void* __restrict__ Wo,
    u16* __restrict__ WT, const int* __restrict__ flag)
{
  __shared__ _Float16 t[64][80];
  const int z = blockIdx.z;
  const void* src = z == 0 ? Wq : z == 1 ? Wk : z == 2 ? Wv : Wo;
  u16* dst = WT + (size_t)z * 1024 * 1024;
  const int bx = blockIdx.x, by = blockIdx.y;
  const int tid = threadIdx.x;
  const int r = tid >> 2, ch = tid & 3;     // 64 rows x 4 chunks of 16
  const int fl = *flag;
  if (fl) {
    const float* s = (const float*)src + (size_t)(by * 64 + r) * 1024 + bx * 64 + ch * 16;
    #pragma unroll
    for (int v = 0; v < 4; ++v) {
      float4 f = ((const float4*)s)[v];
      t[r][ch * 16 + v * 4 + 0] = (_Float16)f.x;
      t[r][ch * 16 + v * 4 + 1] = (_Float16)f.y;
      t[r][ch * 16 + v * 4 + 2] = (_Float16)f.z;
      t[r][ch * 16 + v * 4 + 3] = (_Float16)f.w;
    }
  } else {
    const u16* s = (const u16*)src + (size_t)(by * 64 + r) * 1024 + bx * 64 + ch * 16;
    uint4 a0 = ((const uint4*)s)[0], a1 = ((const uint4*)s)[1];
    u32 wds[8] = {a0.x, a0.y, a0.z, a0.w, a1.x, a1.y, a1.z, a1.w};
    #pragma unroll
    for (int j = 0; j < 8; ++j) {
      t[r][ch * 16 + 2 * j]     = (_Float16)bfu2f((u16)(wds[j] & 0xFFFF));
      t[r][ch * 16 + 2 * j + 1] = (_Float16)bfu2f((u16)(wds[j] >> 16));
    }
  }
  __syncthreads();
  half8 o0, o1;
  #pragma unroll
  for (int i = 0; i < 8; ++i) { o0[i] = t[ch * 16 + i][r]; o1[i] = t[ch * 16 + 8 + i][r]; }
  u16* d = dst + (size_t)(bx * 64 + r) * 1024 + by * 64 + ch * 16;
  *reinterpret_cast<half8*>(d) = o0;
  *reinterpret_cast<half8*>(d + 8) = o1;
}

// ---------------------------------------------------------------------------
// mask -> bit pack (mask dtype self-detected: byte / 16-bit / 32-bit nonzero)
// ---------------------------------------------------------------------------
__global__ __launch_bounds__(256) void mask_bits_kernel(
    const void* __restrict__ mask, u64* __restrict__ mbits)
{
  const u32 w0 = *(const u32*)mask;           // mask[0][0..] all True (global cols)
  int mode;                                   // 0=byte 1=short 2=word
  if (w0 == 0x01010101u) mode = 0;
  else if ((w0 & 0xFFFFu) && (w0 >> 16)) mode = 1;
  else mode = 2;
  const int row = blockIdx.x;
  const int w = threadIdx.x >> 6, l = threadIdx.x & 63;
  for (int i = 0; i < 8; ++i) {
    int jw = w * 8 + i;
    size_t idx = (size_t)row * S + jw * 64 + l;
    bool m;
    if (mode == 0)      m = ((const unsigned char*)mask)[idx] != 0;
    else if (mode == 1) m = ((const u16*)mask)[idx] != 0;
    else                m = ((const u32*)mask)[idx] != 0;
    u64 bal = __ballot(m);
    if (l == 0) mbits[(size_t)row * 32 + jw] = bal;
  }
}

// ---------------------------------------------------------------------------
// GEMM body: C[M][N] = A[M][K] @ Bt[N][K]^T + bias. 64x256 tile, BK=64,
// 4 waves (2x2), wave tile 32x128 (acc[2][8]). LDS 40KB -> 3-4 wg/CU.
// A_DYN=1: A (f32|bf16) reg-staged with inline cvt + swizzled ds_write.
// A_DYN=0: A f16 via gload_lds. B always f16 via gload_lds (8 ops/wave).
// B-fragments loaded inside the n-loop (1 live) to cap VGPR.
// ---------------------------------------------------------------------------
template<int A_DYN, int OUT_DYN>
DEVI void gemm_body(const void* __restrict__ A, const _Float16* __restrict__ Bt,
                    const void* __restrict__ bias, void* __restrict__ C,
                    int fl, int tM, int tN, int N, int K,
                    _Float16* As, _Float16* Bs)
{
  const int tid = threadIdx.x;
  const int w = tid >> 6, l = tid & 63;
  const int wr = w >> 1, wc = w & 1;
  const int lg = l >> 4, lc = l & 15;
  const int rr = l >> 3;
  const int gsw = (l & 7) ^ rr;
  const int rsw = lc & 7;
  const int arow = tid >> 2, ach = tid & 3;   // A reg-stage geometry

  f32x4 acc[2][8] = {};

  for (int k0 = 0; k0 < K; k0 += 64) {
    if (A_DYN) {
      half8 h0, h1;
      if (fl) {
        const float* ap = (const float*)A + (size_t)(tM + arow) * K + k0 + ach * 16;
        float4 f0 = ((const float4*)ap)[0], f1 = ((const float4*)ap)[1];
        float4 f2 = ((const float4*)ap)[2], f3 = ((const float4*)ap)[3];
        h0[0] = (_Float16)f0.x; h0[1] = (_Float16)f0.y;
        h0[2] = (_Float16)f0.z; h0[3] = (_Float16)f0.w;
        h0[4] = (_Float16)f1.x; h0[5] = (_Float16)f1.y;
        h0[6] = (_Float16)f1.z; h0[7] = (_Float16)f1.w;
        h1[0] = (_Float16)f2.x; h1[1] = (_Float16)f2.y;
        h1[2] = (_Float16)f2.z; h1[3] = (_Float16)f2.w;
        h1[4] = (_Float16)f3.x; h1[5] = (_Float16)f3.y;
        h1[6] = (_Float16)f3.z; h1[7] = (_Float16)f3.w;
      } else {
        const u16* ap = (const u16*)A + (size_t)(tM + arow) * K + k0 + ach * 16;
        uint4 a0 = ((const uint4*)ap)[0], a1 = ((const uint4*)ap)[1];
        u32 wd[8] = {a0.x, a0.y, a0.z, a0.w, a1.x, a1.y, a1.z, a1.w};
        #pragma unroll
        for (int j = 0; j < 4; ++j) {
          h0[2 * j]     = (_Float16)bfu2f((u16)(wd[j] & 0xFFFF));
          h0[2 * j + 1] = (_Float16)bfu2f((u16)(wd[j] >> 16));
          h1[2 * j]     = (_Float16)bfu2f((u16)(wd[4 + j] & 0xFFFF));
          h1[2 * j + 1] = (_Float16)bfu2f((u16)(wd[4 + j] >> 16));
        }
      }
      const int c0 = (2 * ach) ^ (arow & 7), c1 = (2 * ach + 1) ^ (arow & 7);
      *reinterpret_cast<half8*>(&As[arow * 64 + c0 * 8]) = h0;
      *reinterpret_cast<half8*>(&As[arow * 64 + c1 * 8]) = h1;
    } else {
      #pragma unroll
      for (int s = 0; s < 2; ++s)
        GLD_LDS16((const _Float16*)A + (size_t)(tM + w * 16 + s * 8 + rr) * K + k0 + gsw * 8,
                  &As[(w * 16 + s * 8) * 64]);
    }
    #pragma unroll
    for (int s = 0; s < 8; ++s)
      GLD_LDS16(Bt + (size_t)(tN + s * 32 + w * 8 + rr) * K + k0 + gsw * 8,
                &Bs[(s * 32 + w * 8) * 64]);
    __syncthreads();
    half8 a[2][2];
    #pragma unroll
    for (int m = 0; m < 2; ++m)
      #pragma unroll
      for (int kk = 0; kk < 2; ++kk)
        a[m][kk] = *reinterpret_cast<const half8*>(
            &As[(wr * 32 + m * 16 + lc) * 64 + ((kk * 4 + lg) ^ rsw) * 8]);
    #pragma unroll
    for (int n = 0; n < 8; ++n) {
      #pragma unroll
      for (int kk = 0; kk < 2; ++kk) {
        half8 b = *reinterpret_cast<const half8*>(
            &Bs[(wc * 128 + n * 16 + lc) * 64 + ((kk * 4 + lg) ^ rsw) * 8]);
        acc[0][n] = mfma_f16_(a[0][kk], b, acc[0][n]);
        acc[1][n] = mfma_f16_(a[1][kk], b, acc[1][n]);
      }
    }
    __syncthreads();
  }

  float bf[8];
  #pragma unroll
  for (int n = 0; n < 8; ++n) {
    int col = tN + wc * 128 + n * 16 + lc;
    bf[n] = fl ? ((const float*)bias)[col] : bfu2f(((const u16*)bias)[col]);
  }
  #pragma unroll
  for (int m = 0; m < 2; ++m) {
    int row = tM + wr * 32 + m * 16 + lg * 4;
    #pragma unroll
    for (int n = 0; n < 8; ++n) {
      int col = tN + wc * 128 + n * 16 + lc;
      #pragma unroll
      for (int r = 0; r < 4; ++r) {
        float v = acc[m][n][r] + bf[n];
        size_t off = (size_t)(row + r) * N + col;
        if (OUT_DYN) {
          if (fl) ((float*)C)[off] = v;
          else    ((u16*)C)[off] = f2bfu(v);
        } else {
          ((u16*)C)[off] = f2hu(v);
        }
      }
    }
  }
}

// Q/K/V projections, one launch, grid.z selects the matrix (fused conversion)
__global__ __launch_bounds__(256) void gemm_qkv(
    const void* __restrict__ Aq, const void* __restrict__ Ak,
    const void* __restrict__ Av, const u16* __restrict__ WT,
    const void* __restrict__ bq, const void* __restrict__ bk,
    const void* __restrict__ bv,
    u16* __restrict__ Qb, u16* __restrict__ Kb, u16* __restrict__ Vb,
    const int* __restrict__ flag)
{
  __shared__ _Float16 As[64 * 64];
  __shared__ _Float16 Bs[256 * 64];
  const int z = blockIdx.z;
  const void* A = z == 0 ? Aq : z == 1 ? Ak : Av;
  const _Float16* Bt = (const _Float16*)(WT + (size_t)z * 1048576);
  const void* bias = z == 0 ? bq : z == 1 ? bk : bv;
  void* C = z == 0 ? Qb : z == 1 ? Kb : Vb;
  gemm_body<1, 0>(A, Bt, bias, C, *flag,
                  blockIdx.x * 64, blockIdx.y * 256, D, D, As, Bs);
}

// output projection (A = Ob f16, C = dyn)
__global__ __launch_bounds__(256) void gemm_o(
    const _Float16* __restrict__ A, const u16* __restrict__ WoT,
    const void* __restrict__ bias, void* __restrict__ C,
    const int* __restrict__ flag)
{
  __shared__ _Float16 As[64 * 64];
  __shared__ _Float16 Bs[256 * 64];
  gemm_body<0, 1>(A, (const _Float16*)WoT, bias, C, *flag,
                  blockIdx.x * 64, blockIdx.y * 256, D, D, As, Bs);
}

// ---------------------------------------------------------------------------
// V [B*S][D] f16 -> vT [B*H][HD][S] f16
// ---------------------------------------------------------------------------
__global__ __launch_bounds__(256) void transpose_v(
    const _Float16* __restrict__ V, _Float16* __restrict__ vT)
{
  __shared__ _Float16 t[64][80];
  const int sb = blockIdx.x, bh = blockIdx.y;
  const int b = bh >> 4, h = bh & 15;
  const int tid = threadIdx.x;
  #pragma unroll
  for (int rep = 0; rep < 2; ++rep) {
    int idx = rep * 256 + tid;
    int sl = idx >> 3, ch = idx & 7;
    *reinterpret_cast<uint4*>(&t[sl][ch * 8]) =
      *reinterpret_cast<const uint4*>(V + (size_t)(b * S + sb * 64 + sl) * D + h * HD + ch * 8);
  }
  __syncthreads();
  #pragma unroll
  for (int rep = 0; rep < 2; ++rep) {
    int idx = rep * 256 + tid;
    int hd = idx >> 3, ch = idx & 7;
    half8 ov;
    #pragma unroll
    for (int i = 0; i < 8; ++i) ov[i] = t[ch * 8 + i][hd];
    *reinterpret_cast<half8*>(vT + ((size_t)bh * HD + hd) * S + sb * 64 + ch * 8) = ov;
  }
}

// ---------------------------------------------------------------------------
// Attention, 128-q-row workgroups (8 waves, 512 thr) — round-15 best.
// ---------------------------------------------------------------------------
__global__ __launch_bounds__(512) void attn_kernel(
    const _Float16* __restrict__ Q, const _Float16* __restrict__ Kp,
    const _Float16* __restrict__ vT, const u64* __restrict__ mbits,
    _Float16* __restrict__ O, void* __restrict__ dOut,
    const int* __restrict__ flag)
{
  __shared__ _Float16 Ks[2][4096];
  __shared__ _Float16 Vs[2][4096];

  const int tid = threadIdx.x, w = tid >> 6, l = tid & 63;
  const int lg = l >> 4, lc = l & 15;
  const int flat = blockIdx.x;                 // 512 wgs
  const int nf = (flat & 7) * 64 + (flat >> 3);  // XCD swizzle (512%8==0)
  const int bh = nf >> 4, rb2 = nf & 15;
  const int b = bh >> 4, h = bh & 15;
  const int wg = w ^ (rb2 & 1);                // balance strided-heavy waves
  const int wrow = rb2 * 128 + wg * 16;
  const int fl = *flag;

  half8 aq[2];
  {
    const _Float16* qp = Q + (size_t)(b * S + wrow + lc) * D + h * HD;
    aq[0] = *reinterpret_cast<const half8*>(qp + lg * 8);
    aq[1] = *reinterpret_cast<const half8*>(qp + 32 + lg * 8);
  }
  const _Float16* kbase = Kp + (size_t)(b * S) * D + h * HD;
  const _Float16* vbase = vT + (size_t)bh * HD * S;
  const u64* mrow = mbits + (size_t)(wrow + lc) * 32;

  const int rr = tid >> 3;                     // 0..63: row staged by this lane
  const int gsw = (l & 7) ^ (rr & 7);          // source-side XOR chunk

  #define STAGE_K(buf, jb) \
    GLD_LDS16(kbase + (size_t)((jb) * 64 + rr) * D + gsw * 8, &Ks[buf][w * 512])
  #define STAGE_V(buf, jb) \
    GLD_LDS16(vbase + (size_t)rr * S + (jb) * 64 + gsw * 8, &Vs[buf][w * 512])

  const int sw = lc & 7;                       // read-side XOR (row&7 == lc&7)

  float rs = 0.f;
  f32x4 accO[4] = {};

  STAGE_K(0, 0);
  STAGE_V(0, 0);
  u64 mb = mrow[0];

  #pragma unroll 1
  for (int jb = 0; jb < 32; ++jb) {
    const int buf = jb & 1;
    BAR();                                     // prev compute done -> overwrite ok
    if (jb < 31) {
      STAGE_K(buf ^ 1, jb + 1);
      STAGE_V(buf ^ 1, jb + 1);
      VMCNT(3);                                // keep mb(1)+stage_next(2); drain tile jb
    } else {
      VMCNT(1);                                // keep mb only
    }
    BAR();                                     // tile jb visible to all waves
    const u64 mb_next = (jb < 31) ? mrow[jb + 1] : 0ull;
    const _Float16* kt = Ks[buf];
    const _Float16* vt = Vs[buf];
    #pragma unroll
    for (int c = 0; c < 4; ++c) {
      const u32 bits = (u32)(mb >> (c * 16 + lg * 4)) & 0xFu;
      if (__any(bits != 0)) {
        const int r = c * 16 + lc;
        half8 ka = *reinterpret_cast<const half8*>(&kt[r * 64 + ((lg ^ sw) * 8)]);
        half8 kb = *reinterpret_cast<const half8*>(&kt[r * 64 + (((lg + 4) ^ sw) * 8)]);
        f32x4 sc = {};
        sc = mfma_f16_(ka, aq[0], sc);
        sc = mfma_f16_(kb, aq[1], sc);
        half4 pa;
        #pragma unroll
        for (int r2 = 0; r2 < 4; ++r2) {
          float p = ((bits >> r2) & 1) ? exp2f(sc[r2] * C_EXP2) : 0.f;
          rs += p;
          pa[r2] = (_Float16)p;
        }
        #pragma unroll
        for (int d = 0; d < 4; ++d) {
          const int rd = d * 16 + lc;
          const int ch = (2 * c + (lg >> 1)) ^ sw;
          half4 vv = *reinterpret_cast<const half4*>(&vt[rd * 64 + ch * 8 + (lg & 1) * 4]);
          accO[d] = mfma16_f16_(pa, vv, accO[d]);
        }
      }
    }
    mb = mb_next;
  }

  rs += __shfl_xor(rs, 16);
  rs += __shfl_xor(rs, 32);
  const float inv = 1.f / rs;
  const float lg2i = -__log2f(rs);

  float invr[4];
  #pragma unroll
  for (int r = 0; r < 4; ++r) invr[r] = __shfl(inv, lg * 4 + r);

  {
    _Float16* op = O + (size_t)(b * S + wrow + lg * 4) * D + h * HD;
    #pragma unroll
    for (int d = 0; d < 4; ++d)
      #pragma unroll
      for (int r = 0; r < 4; ++r)
        op[(size_t)r * D + d * 16 + lc] = (_Float16)(accO[d][r] * invr[r]);
  }

  // sweep 2: recompute scores (K re-staged), normalize via exp2 fma, store
  STAGE_K(0, 0);
  mb = mrow[0];

  if (fl) {
    float* ar = (float*)dOut + OUT_ELEMS + (size_t)bh * S * S + (size_t)(wrow + lc) * S;
    #pragma unroll 1
    for (int jb = 0; jb < 32; ++jb) {
      const int buf = jb & 1;
      BAR();
      if (jb < 31) {
        STAGE_K(buf ^ 1, jb + 1);
        if (jb == 0) VMCNT(2);                 // drain O-stores + stage_0
        else VMCNT(6);                         // keep mb+stores(4)+stage_next
      } else {
        VMCNT(5);                              // keep mb+stores(4); drain stage_31
      }
      BAR();
      const u64 mb_next = (jb < 31) ? mrow[jb + 1] : 0ull;
      const _Float16* kt = Ks[buf];
      #pragma unroll
      for (int c = 0; c < 4; ++c) {
        const u32 bits = (u32)(mb >> (c * 16 + lg * 4)) & 0xFu;
        f32x4* dst = (f32x4*)(ar + jb * 64 + c * 16 + lg * 4);
        if (__any(bits != 0)) {
          const int r = c * 16 + lc;
          half8 ka = *reinterpret_cast<const half8*>(&kt[r * 64 + ((lg ^ sw) * 8)]);
          half8 kb = *reinterpret_cast<const half8*>(&kt[r * 64 + (((lg + 4) ^ sw) * 8)]);
          f32x4 sc = {};
          sc = mfma_f16_(ka, aq[0], sc);
          sc = mfma_f16_(kb, aq[1], sc);
          f32x4 pv;
          #pragma unroll
          for (int r2 = 0; r2 < 4; ++r2)
            pv[r2] = ((bits >> r2) & 1) ? exp2f(__builtin_fmaf(sc[r2], C_EXP2, lg2i)) : 0.f;
          *dst = pv;
        } else {
          f32x4 z = {};
          *dst = z;
        }
      }
      mb = mb_next;
    }
  } else {
    u16* ar = (u16*)dOut + OUT_ELEMS + (size_t)bh * S * S + (size_t)(wrow + lc) * S;
    #pragma unroll 1
    for (int jb = 0; jb < 32; ++jb) {
      const int buf = jb & 1;
      BAR();
      if (jb < 31) {
        STAGE_K(buf ^ 1, jb + 1);
        if (jb == 0) VMCNT(2);
        else VMCNT(6);
      } else {
        VMCNT(5);
      }
      BAR();
      const u64 mb_next = (jb < 31) ? mrow[jb + 1] : 0ull;
      const _Float16* kt = Ks[buf];
      #pragma unroll
      for (int c = 0; c < 4; ++c) {
        const u32 bits = (u32)(mb >> (c * 16 + lg * 4)) & 0xFu;
        u32x2* dst = (u32x2*)(ar + jb * 64 + c * 16 + lg * 4);
        if (__any(bits != 0)) {
          const int r = c * 16 + lc;
          half8 ka = *reinterpret_cast<const half8*>(&kt[r * 64 + ((lg ^ sw) * 8)]);
          half8 kb = *reinterpret_cast<const half8*>(&kt[r * 64 + (((lg + 4) ^ sw) * 8)]);
          f32x4 sc = {};
          sc = mfma_f16_(ka, aq[0], sc);
          sc = mfma_f16_(kb, aq[1], sc);
          float p0 = ((bits >> 0) & 1) ? exp2f(__builtin_fmaf(sc[0], C_EXP2, lg2i)) : 0.f;
          float p1 = ((bits >> 1) & 1) ? exp2f(__builtin_fmaf(sc[1], C_EXP2, lg2i)) : 0.f;
          float p2 = ((bits >> 2) & 1) ? exp2f(__builtin_fmaf(sc[2], C_EXP2, lg2i)) : 0.f;
          float p3 = ((bits >> 3) & 1) ? exp2f(__builtin_fmaf(sc[3], C_EXP2, lg2i)) : 0.f;
          u32x2 pk;
          pk[0] = (u32)f2bfu(p0) | ((u32)f2bfu(p1) << 16);
          pk[1] = (u32)f2bfu(p2) | ((u32)f2bfu(p3) << 16);
          *dst = pk;
        } else {
          u32x2 z = {0, 0};
          *dst = z;
        }
      }
      mb = mb_next;
    }
  }
  #undef STAGE_K
  #undef STAGE_V
}

// ---------------------------------------------------------------------------
extern "C" void kernel_launch(void* const* d_in, const int* in_sizes, int n_in,
                              void* d_out, int out_size, void* d_ws, size_t ws_size,
                              hipStream_t stream) {
  const void* query = d_in[0];
  const void* key_  = d_in[1];
  const void* value = d_in[2];
  const void* Wq = d_in[3];  const void* bq = d_in[4];
  const void* Wk = d_in[5];  const void* bk = d_in[6];
  const void* Wv = d_in[7];  const void* bv = d_in[8];
  const void* Wo = d_in[9];  const void* bo = d_in[10];
  const void* mask = d_in[11];

  char* ws = (char*)d_ws;
  u16* WT   = (u16*)(ws + OFF_WT);
  u16* Qb   = (u16*)(ws + OFF_Q);
  u16* Kb   = (u16*)(ws + OFF_K);
  u16* Vb   = (u16*)(ws + OFF_V);
  u16* vTb  = (u16*)(ws + OFF_VT);
  u16* Ob   = (u16*)(ws + OFF_O);
  u64* mbits = (u64*)(ws + OFF_MB);
  int* flag  = (int*)(ws + OFF_FLG);

  u16* WoT = WT + 3145728;

  detect_dtype<<<1, 256, 0, stream>>>((const u16*)query, flag);
  prep_w<<<dim3(16, 16, 4), 256, 0, stream>>>(Wq, Wk, Wv, Wo, WT, flag);
  mask_bits_kernel<<<dim3(S), 256, 0, stream>>>(mask, mbits);

  gemm_qkv<<<dim3(MROWS / 64, D / 256, 3), 256, 0, stream>>>(
      query, key_, value, WT, bq, bk, bv, Qb, Kb, Vb, flag);

  transpose_v<<<dim3(32, 32), 256, 0, stream>>>((const _Float16*)Vb, (_Float16*)vTb);
  attn_kernel<<<dim3(512), 512, 0, stream>>>(
      (const _Float16*)Qb, (const _Float16*)Kb, (const _Float16*)vTb,
      mbits, (_Float16*)Ob, d_out, flag);
  gemm_o<<<dim3(MROWS / 64, D / 256), 256, 0, stream>>>(
      (const _Float16*)Ob, WoT, bo, d_out, flag);
}

// Round 17
// 314.664 us; speedup vs baseline: 1.0540x; 1.0540x over previous
//
#include <hip/hip_runtime.h>
#include <hip/hip_bf16.h>
#include <hip/hip_fp16.h>

using u16 = unsigned short;
using u32 = unsigned int;
using u64 = unsigned long long;

typedef __attribute__((ext_vector_type(8))) short short8;
typedef __attribute__((ext_vector_type(8))) _Float16 half8;
typedef __attribute__((ext_vector_type(4))) _Float16 half4;
typedef __attribute__((ext_vector_type(4))) float f32x4;
typedef __attribute__((ext_vector_type(2))) u32 u32x2;

#define DEVI static __device__ __forceinline__

DEVI float bfu2f(u16 u) { return __builtin_bit_cast(float, (u32)u << 16); }
DEVI u16 f2bfu(float f) { return __builtin_bit_cast(u16, __float2bfloat16(f)); }
DEVI u16 f2hu(float f) { return __builtin_bit_cast(u16, (_Float16)f); }

DEVI f32x4 mfma_f16_(half8 a, half8 b, f32x4 c) {
  return __builtin_amdgcn_mfma_f32_16x16x32_f16(a, b, c, 0, 0, 0);
}
DEVI f32x4 mfma16_f16_(half4 a, half4 b, f32x4 c) {
  return __builtin_amdgcn_mfma_f32_16x16x16f16(a, b, c, 0, 0, 0);
}

// global -> LDS async stage, 16B per lane, linear dest (wave-uniform base)
#define GLD_LDS16(src, dst) \
  __builtin_amdgcn_global_load_lds((const __attribute__((address_space(1))) void*)(src), \
                                   (__attribute__((address_space(3))) void*)(dst), 16, 0, 0)

#define BAR() __builtin_amdgcn_s_barrier()
#define VMCNT(n) asm volatile("s_waitcnt vmcnt(" #n ")" ::: "memory")

// ---------------------------------------------------------------------------
// constants
// ---------------------------------------------------------------------------
static constexpr int Bsz = 2, S = 2048, D = 1024, H = 16, HD = 64;
static constexpr int MROWS = Bsz * S;                              // 4096
static constexpr size_t OUT_ELEMS = (size_t)Bsz * S * D;           // 4194304
static constexpr float C_EXP2 = 0.18033688f;  // 0.125 * log2(e)
// ws offsets (bytes)
static constexpr size_t OFF_WT  = 0;          // 4 x f16 [1024][1024] = 8MB
static constexpr size_t OFF_Q   = 0x800000;   // f16 [4096][1024] 8MB
static constexpr size_t OFF_K   = 0x1000000;
static constexpr size_t OFF_V   = 0x1800000;
static constexpr size_t OFF_VT  = 0x2000000;  // f16 [B*H][64][2048]
static constexpr size_t OFF_O   = 0x2800000;  // f16 [4096][1024]
static constexpr size_t OFF_MB  = 0x3000000;  // u64 [2048][32]
static constexpr size_t OFF_FLG = 0x3080000;  // int

// ---------------------------------------------------------------------------
// dtype detect
// ---------------------------------------------------------------------------
__global__ __launch_bounds__(256) void detect_dtype(
    const u16* __restrict__ q, int* __restrict__ flag)
{
  __shared__ u32 red[256];
  const int tid = threadIdx.x;
  u32 mx = 0;
  for (int i = tid; i < 32768; i += 256) {
    u32 e = (q[2 * i] >> 7) & 0xFF;
    mx = mx > e ? mx : e;
  }
  red[tid] = mx;
  __syncthreads();
  if (tid == 0) {
    u32 m = 0;
    for (int i = 0; i < 256; ++i) m = m > red[i] ? m : red[i];
    flag[0] = (m >= 0x90) ? 1 : 0;
  }
}

// ---------------------------------------------------------------------------
// W transpose + convert to f16: W[K][N] (f32|bf16) -> WT[z][N][K] f16
// ---------------------------------------------------------------------------
__global__ __launch_bounds__(256) void prep_w(
    const void* __restrict__ Wq, const void* __restrict__ Wk,
    const void* __restrict__ Wv, const void* __restrict__ Wo,
    u16* __restrict__ WT, const int* __restrict__ flag)
{
  __shared__ _Float16 t[64][80];
  const int z = blockIdx.z;
  const void* src = z == 0 ? Wq : z == 1 ? Wk : z == 2 ? Wv : Wo;
  u16* dst = WT + (size_t)z * 1024 * 1024;
  const int bx = blockIdx.x, by = blockIdx.y;
  const int tid = threadIdx.x;
  const int r = tid >> 2, ch = tid & 3;     // 64 rows x 4 chunks of 16
  const int fl = *flag;
  if (fl) {
    const float* s = (const float*)src + (size_t)(by * 64 + r) * 1024 + bx * 64 + ch * 16;
    #pragma unroll
    for (int v = 0; v < 4; ++v) {
      float4 f = ((const float4*)s)[v];
      t[r][ch * 16 + v * 4 + 0] = (_Float16)f.x;
      t[r][ch * 16 + v * 4 + 1] = (_Float16)f.y;
      t[r][ch * 16 + v * 4 + 2] = (_Float16)f.z;
      t[r][ch * 16 + v * 4 + 3] = (_Float16)f.w;
    }
  } else {
    const u16* s = (const u16*)src + (size_t)(by * 64 + r) * 1024 + bx * 64 + ch * 16;
    uint4 a0 = ((const uint4*)s)[0], a1 = ((const uint4*)s)[1];
    u32 wds[8] = {a0.x, a0.y, a0.z, a0.w, a1.x, a1.y, a1.z, a1.w};
    #pragma unroll
    for (int j = 0; j < 8; ++j) {
      t[r][ch * 16 + 2 * j]     = (_Float16)bfu2f((u16)(wds[j] & 0xFFFF));
      t[r][ch * 16 + 2 * j + 1] = (_Float16)bfu2f((u16)(wds[j] >> 16));
    }
  }
  __syncthreads();
  half8 o0, o1;
  #pragma unroll
  for (int i = 0; i < 8; ++i) { o0[i] = t[ch * 16 + i][r]; o1[i] = t[ch * 16 + 8 + i][r]; }
  u16* d = dst + (size_t)(bx * 64 + r) * 1024 + by * 64 + ch * 16;
  *reinterpret_cast<half8*>(d) = o0;
  *reinterpret_cast<half8*>(d + 8) = o1;
}

// ---------------------------------------------------------------------------
// mask -> bit pack (mask dtype self-detected: byte / 16-bit / 32-bit nonzero)
// ---------------------------------------------------------------------------
__global__ __launch_bounds__(256) void mask_bits_kernel(
    const void* __restrict__ mask, u64* __restrict__ mbits)
{
  const u32 w0 = *(const u32*)mask;           // mask[0][0..] all True (global cols)
  int mode;                                   // 0=byte 1=short 2=word
  if (w0 == 0x01010101u) mode = 0;
  else if ((w0 & 0xFFFFu) && (w0 >> 16)) mode = 1;
  else mode = 2;
  const int row = blockIdx.x;
  const int w = threadIdx.x >> 6, l = threadIdx.x & 63;
  for (int i = 0; i < 8; ++i) {
    int jw = w * 8 + i;
    size_t idx = (size_t)row * S + jw * 64 + l;
    bool m;
    if (mode == 0)      m = ((const unsigned char*)mask)[idx] != 0;
    else if (mode == 1) m = ((const u16*)mask)[idx] != 0;
    else                m = ((const u32*)mask)[idx] != 0;
    u64 bal = __ballot(m);
    if (l == 0) mbits[(size_t)row * 32 + jw] = bal;
  }
}

// ---------------------------------------------------------------------------
// GEMM body: C[M][N] = A[M][K] @ Bt[N][K]^T + bias. 64x128 tile, BK=64,
// 4 waves. A_DYN=1: A is (f32|bf16), reg-staged with inline cvt + swizzled
// ds_write_b128. A_DYN=0: A f16 via gload_lds. B always f16 via gload_lds.
// ---------------------------------------------------------------------------
template<int A_DYN, int OUT_DYN>
DEVI void gemm_body(const void* __restrict__ A, const _Float16* __restrict__ Bt,
                    const void* __restrict__ bias, void* __restrict__ C,
                    int fl, int tM, int tN, int N, int K,
                    _Float16* As, _Float16* Bs)
{
  const int tid = threadIdx.x;
  const int w = tid >> 6, l = tid & 63;
  const int wr = w >> 1, wc = w & 1;
  const int lg = l >> 4, lc = l & 15;
  const int rr = l >> 3;
  const int gsw = (l & 7) ^ rr;
  const int rsw = lc & 7;
  const int arow = tid >> 2, ach = tid & 3;   // A reg-stage geometry

  f32x4 acc[2][4] = {};

  for (int k0 = 0; k0 < K; k0 += 64) {
    if (A_DYN) {
      half8 h0, h1;
      if (fl) {
        const float* ap = (const float*)A + (size_t)(tM + arow) * K + k0 + ach * 16;
        float4 f0 = ((const float4*)ap)[0], f1 = ((const float4*)ap)[1];
        float4 f2 = ((const float4*)ap)[2], f3 = ((const float4*)ap)[3];
        h0[0] = (_Float16)f0.x; h0[1] = (_Float16)f0.y;
        h0[2] = (_Float16)f0.z; h0[3] = (_Float16)f0.w;
        h0[4] = (_Float16)f1.x; h0[5] = (_Float16)f1.y;
        h0[6] = (_Float16)f1.z; h0[7] = (_Float16)f1.w;
        h1[0] = (_Float16)f2.x; h1[1] = (_Float16)f2.y;
        h1[2] = (_Float16)f2.z; h1[3] = (_Float16)f2.w;
        h1[4] = (_Float16)f3.x; h1[5] = (_Float16)f3.y;
        h1[6] = (_Float16)f3.z; h1[7] = (_Float16)f3.w;
      } else {
        const u16* ap = (const u16*)A + (size_t)(tM + arow) * K + k0 + ach * 16;
        uint4 a0 = ((const uint4*)ap)[0], a1 = ((const uint4*)ap)[1];
        u32 wd[8] = {a0.x, a0.y, a0.z, a0.w, a1.x, a1.y, a1.z, a1.w};
        #pragma unroll
        for (int j = 0; j < 4; ++j) {
          h0[2 * j]     = (_Float16)bfu2f((u16)(wd[j] & 0xFFFF));
          h0[2 * j + 1] = (_Float16)bfu2f((u16)(wd[j] >> 16));
          h1[2 * j]     = (_Float16)bfu2f((u16)(wd[4 + j] & 0xFFFF));
          h1[2 * j + 1] = (_Float16)bfu2f((u16)(wd[4 + j] >> 16));
        }
      }
      const int c0 = (2 * ach) ^ (arow & 7), c1 = (2 * ach + 1) ^ (arow & 7);
      *reinterpret_cast<half8*>(&As[arow * 64 + c0 * 8]) = h0;
      *reinterpret_cast<half8*>(&As[arow * 64 + c1 * 8]) = h1;
    } else {
      #pragma unroll
      for (int s = 0; s < 2; ++s)
        GLD_LDS16((const _Float16*)A + (size_t)(tM + w * 16 + s * 8 + rr) * K + k0 + gsw * 8,
                  &As[(w * 16 + s * 8) * 64]);
    }
    #pragma unroll
    for (int s = 0; s < 4; ++s)
      GLD_LDS16(Bt + (size_t)(tN + w * 32 + s * 8 + rr) * K + k0 + gsw * 8,
                &Bs[(w * 32 + s * 8) * 64]);
    __syncthreads();
    half8 a[2][2], b[4][2];
    #pragma unroll
    for (int m = 0; m < 2; ++m)
      #pragma unroll
      for (int kk = 0; kk < 2; ++kk)
        a[m][kk] = *reinterpret_cast<const half8*>(
            &As[(wr * 32 + m * 16 + lc) * 64 + ((kk * 4 + lg) ^ rsw) * 8]);
    #pragma unroll
    for (int n = 0; n < 4; ++n)
      #pragma unroll
      for (int kk = 0; kk < 2; ++kk)
        b[n][kk] = *reinterpret_cast<const half8*>(
            &Bs[(wc * 64 + n * 16 + lc) * 64 + ((kk * 4 + lg) ^ rsw) * 8]);
    #pragma unroll
    for (int m = 0; m < 2; ++m)
      #pragma unroll
      for (int n = 0; n < 4; ++n) {
        acc[m][n] = mfma_f16_(a[m][0], b[n][0], acc[m][n]);
        acc[m][n] = mfma_f16_(a[m][1], b[n][1], acc[m][n]);
      }
    __syncthreads();
  }

  float bf[4];
  #pragma unroll
  for (int n = 0; n < 4; ++n) {
    int col = tN + wc * 64 + n * 16 + lc;
    bf[n] = fl ? ((const float*)bias)[col] : bfu2f(((const u16*)bias)[col]);
  }
  #pragma unroll
  for (int m = 0; m < 2; ++m) {
    int row = tM + wr * 32 + m * 16 + lg * 4;
    #pragma unroll
    for (int n = 0; n < 4; ++n) {
      int col = tN + wc * 64 + n * 16 + lc;
      #pragma unroll
      for (int r = 0; r < 4; ++r) {
        float v = acc[m][n][r] + bf[n];
        size_t off = (size_t)(row + r) * N + col;
        if (OUT_DYN) {
          if (fl) ((float*)C)[off] = v;
          else    ((u16*)C)[off] = f2bfu(v);
        } else {
          ((u16*)C)[off] = f2hu(v);
        }
      }
    }
  }
}

// Q/K/V projections, one launch, grid.z selects the matrix (fused conversion)
__global__ __launch_bounds__(256) void gemm_qkv(
    const void* __restrict__ Aq, const void* __restrict__ Ak,
    const void* __restrict__ Av, const u16* __restrict__ WT,
    const void* __restrict__ bq, const void* __restrict__ bk,
    const void* __restrict__ bv,
    u16* __restrict__ Qb, u16* __restrict__ Kb, u16* __restrict__ Vb,
    const int* __restrict__ flag)
{
  __shared__ _Float16 As[64 * 64];
  __shared__ _Float16 Bs[128 * 64];
  const int z = blockIdx.z;
  const void* A = z == 0 ? Aq : z == 1 ? Ak : Av;
  const _Float16* Bt = (const _Float16*)(WT + (size_t)z * 1048576);
  const void* bias = z == 0 ? bq : z == 1 ? bk : bv;
  void* C = z == 0 ? Qb : z == 1 ? Kb : Vb;
  gemm_body<1, 0>(A, Bt, bias, C, *flag,
                  blockIdx.x * 64, blockIdx.y * 128, D, D, As, Bs);
}

// output projection (A = Ob f16, C = dyn)
__global__ __launch_bounds__(256) void gemm_o(
    const _Float16* __restrict__ A, const u16* __restrict__ WoT,
    const void* __restrict__ bias, void* __restrict__ C,
    const int* __restrict__ flag)
{
  __shared__ _Float16 As[64 * 64];
  __shared__ _Float16 Bs[128 * 64];
  gemm_body<0, 1>(A, (const _Float16*)WoT, bias, C, *flag,
                  blockIdx.x * 64, blockIdx.y * 128, D, D, As, Bs);
}

// ---------------------------------------------------------------------------
// V [B*S][D] f16 -> vT [B*H][HD][S] f16
// ---------------------------------------------------------------------------
__global__ __launch_bounds__(256) void transpose_v(
    const _Float16* __restrict__ V, _Float16* __restrict__ vT)
{
  __shared__ _Float16 t[64][80];
  const int sb = blockIdx.x, bh = blockIdx.y;
  const int b = bh >> 4, h = bh & 15;
  const int tid = threadIdx.x;
  #pragma unroll
  for (int rep = 0; rep < 2; ++rep) {
    int idx = rep * 256 + tid;
    int sl = idx >> 3, ch = idx & 7;
    *reinterpret_cast<uint4*>(&t[sl][ch * 8]) =
      *reinterpret_cast<const uint4*>(V + (size_t)(b * S + sb * 64 + sl) * D + h * HD + ch * 8);
  }
  __syncthreads();
  #pragma unroll
  for (int rep = 0; rep < 2; ++rep) {
    int idx = rep * 256 + tid;
    int hd = idx >> 3, ch = idx & 7;
    half8 ov;
    #pragma unroll
    for (int i = 0; i < 8; ++i) ov[i] = t[ch * 8 + i][hd];
    *reinterpret_cast<half8*>(vT + ((size_t)bh * HD + hd) * S + sb * 64 + ch * 8) = ov;
  }
}

// ---------------------------------------------------------------------------
// Attention, 128-q-row workgroups (8 waves, 512 thr) — round-15 best.
// ---------------------------------------------------------------------------
__global__ __launch_bounds__(512) void attn_kernel(
    const _Float16* __restrict__ Q, const _Float16* __restrict__ Kp,
    const _Float16* __restrict__ vT, const u64* __restrict__ mbits,
    _Float16* __restrict__ O, void* __restrict__ dOut,
    const int* __restrict__ flag)
{
  __shared__ _Float16 Ks[2][4096];
  __shared__ _Float16 Vs[2][4096];

  const int tid = threadIdx.x, w = tid >> 6, l = tid & 63;
  const int lg = l >> 4, lc = l & 15;
  const int flat = blockIdx.x;                 // 512 wgs
  const int nf = (flat & 7) * 64 + (flat >> 3);  // XCD swizzle (512%8==0)
  const int bh = nf >> 4, rb2 = nf & 15;
  const int b = bh >> 4, h = bh & 15;
  const int wg = w ^ (rb2 & 1);                // balance strided-heavy waves
  const int wrow = rb2 * 128 + wg * 16;
  const int fl = *flag;

  half8 aq[2];
  {
    const _Float16* qp = Q + (size_t)(b * S + wrow + lc) * D + h * HD;
    aq[0] = *reinterpret_cast<const half8*>(qp + lg * 8);
    aq[1] = *reinterpret_cast<const half8*>(qp + 32 + lg * 8);
  }
  const _Float16* kbase = Kp + (size_t)(b * S) * D + h * HD;
  const _Float16* vbase = vT + (size_t)bh * HD * S;
  const u64* mrow = mbits + (size_t)(wrow + lc) * 32;

  const int rr = tid >> 3;                     // 0..63: row staged by this lane
  const int gsw = (l & 7) ^ (rr & 7);          // source-side XOR chunk

  #define STAGE_K(buf, jb) \
    GLD_LDS16(kbase + (size_t)((jb) * 64 + rr) * D + gsw * 8, &Ks[buf][w * 512])
  #define STAGE_V(buf, jb) \
    GLD_LDS16(vbase + (size_t)rr * S + (jb) * 64 + gsw * 8, &Vs[buf][w * 512])

  const int sw = lc & 7;                       // read-side XOR (row&7 == lc&7)

  float rs = 0.f;
  f32x4 accO[4] = {};

  STAGE_K(0, 0);
  STAGE_V(0, 0);
  u64 mb = mrow[0];

  #pragma unroll 1
  for (int jb = 0; jb < 32; ++jb) {
    const int buf = jb & 1;
    BAR();                                     // prev compute done -> overwrite ok
    if (jb < 31) {
      STAGE_K(buf ^ 1, jb + 1);
      STAGE_V(buf ^ 1, jb + 1);
      VMCNT(3);                                // keep mb(1)+stage_next(2); drain tile jb
    } else {
      VMCNT(1);                                // keep mb only
    }
    BAR();                                     // tile jb visible to all waves
    const u64 mb_next = (jb < 31) ? mrow[jb + 1] : 0ull;
    const _Float16* kt = Ks[buf];
    const _Float16* vt = Vs[buf];
    #pragma unroll
    for (int c = 0; c < 4; ++c) {
      const u32 bits = (u32)(mb >> (c * 16 + lg * 4)) & 0xFu;
      if (__any(bits != 0)) {
        const int r = c * 16 + lc;
        half8 ka = *reinterpret_cast<const half8*>(&kt[r * 64 + ((lg ^ sw) * 8)]);
        half8 kb = *reinterpret_cast<const half8*>(&kt[r * 64 + (((lg + 4) ^ sw) * 8)]);
        f32x4 sc = {};
        sc = mfma_f16_(ka, aq[0], sc);
        sc = mfma_f16_(kb, aq[1], sc);
        half4 pa;
        #pragma unroll
        for (int r2 = 0; r2 < 4; ++r2) {
          float p = ((bits >> r2) & 1) ? exp2f(sc[r2] * C_EXP2) : 0.f;
          rs += p;
          pa[r2] = (_Float16)p;
        }
        #pragma unroll
        for (int d = 0; d < 4; ++d) {
          const int rd = d * 16 + lc;
          const int ch = (2 * c + (lg >> 1)) ^ sw;
          half4 vv = *reinterpret_cast<const half4*>(&vt[rd * 64 + ch * 8 + (lg & 1) * 4]);
          accO[d] = mfma16_f16_(pa, vv, accO[d]);
        }
      }
    }
    mb = mb_next;
  }

  rs += __shfl_xor(rs, 16);
  rs += __shfl_xor(rs, 32);
  const float inv = 1.f / rs;
  const float lg2i = -__log2f(rs);

  float invr[4];
  #pragma unroll
  for (int r = 0; r < 4; ++r) invr[r] = __shfl(inv, lg * 4 + r);

  {
    _Float16* op = O + (size_t)(b * S + wrow + lg * 4) * D + h * HD;
    #pragma unroll
    for (int d = 0; d < 4; ++d)
      #pragma unroll
      for (int r = 0; r < 4; ++r)
        op[(size_t)r * D + d * 16 + lc] = (_Float16)(accO[d][r] * invr[r]);
  }

  // sweep 2: recompute scores (K re-staged), normalize via exp2 fma, store
  STAGE_K(0, 0);
  mb = mrow[0];

  if (fl) {
    float* ar = (float*)dOut + OUT_ELEMS + (size_t)bh * S * S + (size_t)(wrow + lc) * S;
    #pragma unroll 1
    for (int jb = 0; jb < 32; ++jb) {
      const int buf = jb & 1;
      BAR();
      if (jb < 31) {
        STAGE_K(buf ^ 1, jb + 1);
        if (jb == 0) VMCNT(2);                 // drain O-stores + stage_0
        else VMCNT(6);                         // keep mb+stores(4)+stage_next
      } else {
        VMCNT(5);                              // keep mb+stores(4); drain stage_31
      }
      BAR();
      const u64 mb_next = (jb < 31) ? mrow[jb + 1] : 0ull;
      const _Float16* kt = Ks[buf];
      #pragma unroll
      for (int c = 0; c < 4; ++c) {
        const u32 bits = (u32)(mb >> (c * 16 + lg * 4)) & 0xFu;
        f32x4* dst = (f32x4*)(ar + jb * 64 + c * 16 + lg * 4);
        if (__any(bits != 0)) {
          const int r = c * 16 + lc;
          half8 ka = *reinterpret_cast<const half8*>(&kt[r * 64 + ((lg ^ sw) * 8)]);
          half8 kb = *reinterpret_cast<const half8*>(&kt[r * 64 + (((lg + 4) ^ sw) * 8)]);
          f32x4 sc = {};
          sc = mfma_f16_(ka, aq[0], sc);
          sc = mfma_f16_(kb, aq[1], sc);
          f32x4 pv;
          #pragma unroll
          for (int r2 = 0; r2 < 4; ++r2)
            pv[r2] = ((bits >> r2) & 1) ? exp2f(__builtin_fmaf(sc[r2], C_EXP2, lg2i)) : 0.f;
          *dst = pv;
        } else {
          f32x4 z = {};
          *dst = z;
        }
      }
      mb = mb_next;
    }
  } else {
    u16* ar = (u16*)dOut + OUT_ELEMS + (size_t)bh * S * S + (size_t)(wrow + lc) * S;
    #pragma unroll 1
    for (int jb = 0; jb < 32; ++jb) {
      const int buf = jb & 1;
      BAR();
      if (jb < 31) {
        STAGE_K(buf ^ 1, jb + 1);
        if (jb == 0) VMCNT(2);
        else VMCNT(6);
      } else {
        VMCNT(5);
      }
      BAR();
      const u64 mb_next = (jb < 31) ? mrow[jb + 1] : 0ull;
      const _Float16* kt = Ks[buf];
      #pragma unroll
      for (int c = 0; c < 4; ++c) {
        const u32 bits = (u32)(mb >> (c * 16 + lg * 4)) & 0xFu;
        u32x2* dst = (u32x2*)(ar + jb * 64 + c * 16 + lg * 4);
        if (__any(bits != 0)) {
          const int r = c * 16 + lc;
          half8 ka = *reinterpret_cast<const half8*>(&kt[r * 64 + ((lg ^ sw) * 8)]);
          half8 kb = *reinterpret_cast<const half8*>(&kt[r * 64 + (((lg + 4) ^ sw) * 8)]);
          f32x4 sc = {};
          sc = mfma_f16_(ka, aq[0], sc);
          sc = mfma_f16_(kb, aq[1], sc);
          float p0 = ((bits >> 0) & 1) ? exp2f(__builtin_fmaf(sc[0], C_EXP2, lg2i)) : 0.f;
          float p1 = ((bits >> 1) & 1) ? exp2f(__builtin_fmaf(sc[1], C_EXP2, lg2i)) : 0.f;
          float p2 = ((bits >> 2) & 1) ? exp2f(__builtin_fmaf(sc[2], C_EXP2, lg2i)) : 0.f;
          float p3 = ((bits >> 3) & 1) ? exp2f(__builtin_fmaf(sc[3], C_EXP2, lg2i)) : 0.f;
          u32x2 pk;
          pk[0] = (u32)f2bfu(p0) | ((u32)f2bfu(p1) << 16);
          pk[1] = (u32)f2bfu(p2) | ((u32)f2bfu(p3) << 16);
          *dst = pk;
        } else {
          u32x2 z = {0, 0};
          *dst = z;
        }
      }
      mb = mb_next;
    }
  }
  #undef STAGE_K
  #undef STAGE_V
}

// ---------------------------------------------------------------------------
extern "C" void kernel_launch(void* const* d_in, const int* in_sizes, int n_in,
                              void* d_out, int out_size, void* d_ws, size_t ws_size,
                              hipStream_t stream) {
  const void* query = d_in[0];
  const void* key_  = d_in[1];
  const void* value = d_in[2];
  const void* Wq = d_in[3];  const void* bq = d_in[4];
  const void* Wk = d_in[5];  const void* bk = d_in[6];
  const void* Wv = d_in[7];  const void* bv = d_in[8];
  const void* Wo = d_in[9];  const void* bo = d_in[10];
  const void* mask = d_in[11];

  char* ws = (char*)d_ws;
  u16* WT   = (u16*)(ws + OFF_WT);
  u16* Qb   = (u16*)(ws + OFF_Q);
  u16* Kb   = (u16*)(ws + OFF_K);
  u16* Vb   = (u16*)(ws + OFF_V);
  u16* vTb  = (u16*)(ws + OFF_VT);
  u16* Ob   = (u16*)(ws + OFF_O);
  u64* mbits = (u64*)(ws + OFF_MB);
  int* flag  = (int*)(ws + OFF_FLG);

  u16* WoT = WT + 3145728;

  detect_dtype<<<1, 256, 0, stream>>>((const u16*)query, flag);
  prep_w<<<dim3(16, 16, 4), 256, 0, stream>>>(Wq, Wk, Wv, Wo, WT, flag);
  mask_bits_kernel<<<dim3(S), 256, 0, stream>>>(mask, mbits);

  gemm_qkv<<<dim3(MROWS / 64, D / 128, 3), 256, 0, stream>>>(
      query, key_, value, WT, bq, bk, bv, Qb, Kb, Vb, flag);

  transpose_v<<<dim3(32, 32), 256, 0, stream>>>((const _Float16*)Vb, (_Float16*)vTb);
  attn_kernel<<<dim3(512), 512, 0, stream>>>(
      (const _Float16*)Qb, (const _Float16*)Kb, (const _Float16*)vTb,
      mbits, (_Float16*)Ob, d_out, flag);
  gemm_o<<<dim3(MROWS / 64, D / 128), 256, 0, stream>>>(
      (const _Float16*)Ob, WoT, bo, d_out, flag);
}